// Round 1
// baseline (1159.028 us; speedup 1.0000x reference)
//
#include <hip/hip_runtime.h>
#include <hip/hip_fp16.h>

// Problem constants (from reference)
#define M_TOTAL 4096    // BATCH*SEQ = 2*2048
#define N_TOTAL 11008   // OUT_FEATURES
#define K_TOTAL 4096    // IN_FEATURES
#define KPACK   2048    // packed int32 cols = K/2

// Tiling
#define BM 128
#define BN 128
#define BK 32
#define LDSPAD 8              // +8 halves (16B) per row: breaks bank conflicts, keeps 16B alignment
#define LDR (BK + LDSPAD)     // LDS row stride in halves (40)

typedef _Float16 f16x4 __attribute__((ext_vector_type(4)));
typedef _Float16 f16x8 __attribute__((ext_vector_type(8)));
typedef float    f32x4 __attribute__((ext_vector_type(4)));

__global__ __launch_bounds__(256)
void _Int4Linear_54631984005366_kernel(const float* __restrict__ x,
                                       const int*   __restrict__ wp,
                                       const float* __restrict__ scale,
                                       const float* __restrict__ bias,
                                       float*       __restrict__ out)
{
    __shared__ _Float16 As[BM * LDR];
    __shared__ _Float16 Bs[BN * LDR];

    const int t    = threadIdx.x;
    const int wave = t >> 6;
    const int lane = t & 63;
    const int l16  = lane & 15;
    const int quad = lane >> 4;

    const int nBase = blockIdx.x * BN;
    const int mBase = blockIdx.y * BM;

    // wave tile origin within the 128x128 block tile (2x2 waves of 64x64)
    const int wm = (wave >> 1) * 64;
    const int wn = (wave & 1) * 64;

    f32x4 acc[4][4] = {};

    for (int k0 = 0; k0 < K_TOTAL; k0 += BK) {
        // ---- stage A: 128 rows x 32 fp32 -> f16 LDS. 1024 float4 / 256 thr = 4 each ----
        #pragma unroll
        for (int i = 0; i < 4; ++i) {
            const int li  = i * 256 + t;
            const int row = li >> 3;       // 8 float4 per row
            const int c4  = li & 7;
            const float4 v = *(const float4*)(&x[(size_t)(mBase + row) * K_TOTAL + k0 + c4 * 4]);
            f16x4 hv = { (_Float16)v.x, (_Float16)v.y, (_Float16)v.z, (_Float16)v.w };
            *(f16x4*)(&As[row * LDR + c4 * 4]) = hv;   // 8B write, 8B aligned (80*row + 8*c4)
        }

        // ---- stage B: 128 rows x 16 int32 (=32 int4 weights) -> f16 LDS. 512 int4 / 256 thr = 2 each ----
        #pragma unroll
        for (int i = 0; i < 2; ++i) {
            const int li  = i * 256 + t;
            const int row = li >> 2;       // 4 int32x4 per row
            const int c4  = li & 3;
            const int4 p = *(const int4*)(&wp[(size_t)(nBase + row) * KPACK + (k0 >> 1) + c4 * 4]);
            const int vals[4] = { p.x, p.y, p.z, p.w };
            f16x8 hv;
            #pragma unroll
            for (int j = 0; j < 4; ++j) {
                hv[2 * j]     = (_Float16)(( vals[j]       & 15) - 8);  // lo nibble -> k even
                hv[2 * j + 1] = (_Float16)(((vals[j] >> 4) & 15) - 8);  // hi nibble -> k odd
            }
            *(f16x8*)(&Bs[row * LDR + c4 * 8]) = hv;   // 16B write, 16B aligned (80*row + 16*c4)
        }

        __syncthreads();

        // ---- fragments: A[m=l16][k=quad*8+j], B likewise (NT gemm: both k-contiguous) ----
        f16x8 a[4], b[4];
        #pragma unroll
        for (int mt = 0; mt < 4; ++mt)
            a[mt] = *(const f16x8*)(&As[(wm + mt * 16 + l16) * LDR + quad * 8]);
        #pragma unroll
        for (int nt = 0; nt < 4; ++nt)
            b[nt] = *(const f16x8*)(&Bs[(wn + nt * 16 + l16) * LDR + quad * 8]);

        #pragma unroll
        for (int mt = 0; mt < 4; ++mt)
            #pragma unroll
            for (int nt = 0; nt < 4; ++nt)
                acc[mt][nt] = __builtin_amdgcn_mfma_f32_16x16x32_f16(a[mt], b[nt], acc[mt][nt], 0, 0, 0);

        __syncthreads();
    }

    // ---- epilogue: D[m=quad*4+r][n=l16]; out = acc*scale[n] + bias[n] ----
    #pragma unroll
    for (int nt = 0; nt < 4; ++nt) {
        const int n = nBase + wn + nt * 16 + l16;
        const float s  = scale[n];
        const float bz = bias[n];
        #pragma unroll
        for (int mt = 0; mt < 4; ++mt) {
            #pragma unroll
            for (int r = 0; r < 4; ++r) {
                const int m = mBase + wm + mt * 16 + quad * 4 + r;
                out[(size_t)m * N_TOTAL + n] = acc[mt][nt][r] * s + bz;
            }
        }
    }
}

extern "C" void kernel_launch(void* const* d_in, const int* in_sizes, int n_in,
                              void* d_out, int out_size, void* d_ws, size_t ws_size,
                              hipStream_t stream) {
    const float* x     = (const float*)d_in[0];
    const int*   wp    = (const int*)d_in[1];
    const float* scale = (const float*)d_in[2];
    const float* bias  = (const float*)d_in[3];
    float*       out   = (float*)d_out;

    dim3 grid(N_TOTAL / BN, M_TOTAL / BM);   // (86, 32)
    _Int4Linear_54631984005366_kernel<<<grid, 256, 0, stream>>>(x, wp, scale, bias, out);
}

// Round 2
// 875.257 us; speedup vs baseline: 1.3242x; 1.3242x over previous
//
#include <hip/hip_runtime.h>
#include <hip/hip_fp16.h>

#define M_TOTAL 4096
#define N_TOTAL 11008
#define K_TOTAL 4096
#define KPACK   2048     // int32 cols; each int32 holds ONE byte = 2 nibbles

#define BM 128
#define BN 128
#define BK 32            // halves per K-tile; row = 64 B in LDS (unpadded, global_load_lds layout)

typedef _Float16 f16x4 __attribute__((ext_vector_type(4)));
typedef _Float16 f16x8 __attribute__((ext_vector_type(8)));
typedef float    f32x4 __attribute__((ext_vector_type(4)));

// ---------------- async 16B global -> LDS ----------------
__device__ __forceinline__ void load16_to_lds(const void* g, void* l) {
    __builtin_amdgcn_global_load_lds(
        (const __attribute__((address_space(1))) unsigned int*)g,
        (__attribute__((address_space(3))) unsigned int*)l,
        16, 0, 0);
}

// ---------------- prepass 1: x fp32 -> f16 (16.7M elems, 8/thread) ----------------
__global__ __launch_bounds__(256)
void _Int4Linear_cvt_x(const float* __restrict__ x, _Float16* __restrict__ xf) {
    const size_t i = ((size_t)blockIdx.x * 256 + threadIdx.x) * 8;
    const float4 v0 = *(const float4*)(x + i);
    const float4 v1 = *(const float4*)(x + i + 4);
    f16x8 h = { (_Float16)v0.x, (_Float16)v0.y, (_Float16)v0.z, (_Float16)v0.w,
                (_Float16)v1.x, (_Float16)v1.y, (_Float16)v1.z, (_Float16)v1.w };
    *(f16x8*)(xf + i) = h;
}

// ---------------- prepass 2: wp int32 -> f16 pairs (22.5M int32, 4/thread) ----------------
__global__ __launch_bounds__(256)
void _Int4Linear_dequant_w(const int* __restrict__ wp, _Float16* __restrict__ wf) {
    const size_t i = ((size_t)blockIdx.x * 256 + threadIdx.x) * 4;   // int32 index
    const int4 p = *(const int4*)(wp + i);
    const int v[4] = { p.x, p.y, p.z, p.w };
    f16x8 h;
    #pragma unroll
    for (int j = 0; j < 4; ++j) {
        h[2 * j]     = (_Float16)(( v[j]       & 15) - 8);
        h[2 * j + 1] = (_Float16)(((v[j] >> 4) & 15) - 8);
    }
    *(f16x8*)(wf + i * 2) = h;   // each int32 -> 2 f16
}

// ---------------- main GEMM: m97 structure (global_load_lds w=16, unpadded LDS) ----------------
__global__ __launch_bounds__(256)
void _Int4Linear_54631984005366_kernel(const _Float16* __restrict__ A,   // [M][K] f16
                                       const _Float16* __restrict__ B,   // [N][K] f16
                                       const float* __restrict__ scale,
                                       const float* __restrict__ bias,
                                       float*       __restrict__ out)
{
    __shared__ _Float16 As[BM * BK];   // 8 KB, row stride 32 halves = 64 B, NO pad
    __shared__ _Float16 Bs[BN * BK];   // 8 KB

    const int t    = threadIdx.x;
    const int wave = t >> 6;
    const int lane = t & 63;
    const int l16  = lane & 15;
    const int quad = lane >> 4;

    const int nBase = blockIdx.x * BN;
    const int mBase = blockIdx.y * BM;
    const int wm = (wave >> 1) * 64;
    const int wn = (wave & 1) * 64;

    // staging lane map: lane i covers row (i>>2), 16B chunk (i&3) within a 16-row slab
    const int srow   = lane >> 2;        // 0..15
    const int schunk = (lane & 3) * 8;   // halves

    f32x4 acc[4][4] = {};

    for (int k0 = 0; k0 < K_TOTAL; k0 += BK) {
        #pragma unroll
        for (int is = 0; is < 2; ++is) {
            const int rb = wave * 16 + is * 64;   // slab base row (uniform per wave)
            load16_to_lds(&A[(size_t)(mBase + rb + srow) * K_TOTAL + k0 + schunk], &As[rb * BK]);
            load16_to_lds(&B[(size_t)(nBase + rb + srow) * K_TOTAL + k0 + schunk], &Bs[rb * BK]);
        }
        __syncthreads();   // drains vmcnt, then barrier

        f16x8 a[4], b[4];
        #pragma unroll
        for (int mt = 0; mt < 4; ++mt)
            a[mt] = *(const f16x8*)(&As[(wm + mt * 16 + l16) * BK + quad * 8]);
        #pragma unroll
        for (int nt = 0; nt < 4; ++nt)
            b[nt] = *(const f16x8*)(&Bs[(wn + nt * 16 + l16) * BK + quad * 8]);

        #pragma unroll
        for (int mt = 0; mt < 4; ++mt)
            #pragma unroll
            for (int nt = 0; nt < 4; ++nt)
                acc[mt][nt] = __builtin_amdgcn_mfma_f32_16x16x32_f16(a[mt], b[nt], acc[mt][nt], 0, 0, 0);

        __syncthreads();
    }

    #pragma unroll
    for (int nt = 0; nt < 4; ++nt) {
        const int n = nBase + wn + nt * 16 + l16;
        const float s  = scale[n];
        const float bz = bias[n];
        #pragma unroll
        for (int mt = 0; mt < 4; ++mt) {
            #pragma unroll
            for (int r = 0; r < 4; ++r) {
                const int m = mBase + wm + mt * 16 + quad * 4 + r;
                out[(size_t)m * N_TOTAL + n] = acc[mt][nt][r] * s + bz;
            }
        }
    }
}

// ---------------- fallback (R1 kernel): used only if ws too small ----------------
#define LDR 40
__global__ __launch_bounds__(256)
void _Int4Linear_fallback(const float* __restrict__ x, const int* __restrict__ wp,
                          const float* __restrict__ scale, const float* __restrict__ bias,
                          float* __restrict__ out)
{
    __shared__ _Float16 As[BM * LDR];
    __shared__ _Float16 Bs[BN * LDR];
    const int t = threadIdx.x, wave = t >> 6, lane = t & 63;
    const int l16 = lane & 15, quad = lane >> 4;
    const int nBase = blockIdx.x * BN, mBase = blockIdx.y * BM;
    const int wm = (wave >> 1) * 64, wn = (wave & 1) * 64;
    f32x4 acc[4][4] = {};
    for (int k0 = 0; k0 < K_TOTAL; k0 += BK) {
        #pragma unroll
        for (int i = 0; i < 4; ++i) {
            const int li = i * 256 + t, row = li >> 3, c4 = li & 7;
            const float4 v = *(const float4*)(&x[(size_t)(mBase + row) * K_TOTAL + k0 + c4 * 4]);
            f16x4 hv = { (_Float16)v.x, (_Float16)v.y, (_Float16)v.z, (_Float16)v.w };
            *(f16x4*)(&As[row * LDR + c4 * 4]) = hv;
        }
        #pragma unroll
        for (int i = 0; i < 2; ++i) {
            const int li = i * 256 + t, row = li >> 2, c4 = li & 3;
            const int4 p = *(const int4*)(&wp[(size_t)(nBase + row) * KPACK + (k0 >> 1) + c4 * 4]);
            const int vals[4] = { p.x, p.y, p.z, p.w };
            f16x8 hv;
            #pragma unroll
            for (int j = 0; j < 4; ++j) {
                hv[2 * j]     = (_Float16)(( vals[j]       & 15) - 8);
                hv[2 * j + 1] = (_Float16)(((vals[j] >> 4) & 15) - 8);
            }
            *(f16x8*)(&Bs[row * LDR + c4 * 8]) = hv;
        }
        __syncthreads();
        f16x8 a[4], b[4];
        #pragma unroll
        for (int mt = 0; mt < 4; ++mt)
            a[mt] = *(const f16x8*)(&As[(wm + mt * 16 + l16) * LDR + quad * 8]);
        #pragma unroll
        for (int nt = 0; nt < 4; ++nt)
            b[nt] = *(const f16x8*)(&Bs[(wn + nt * 16 + l16) * LDR + quad * 8]);
        #pragma unroll
        for (int mt = 0; mt < 4; ++mt)
            #pragma unroll
            for (int nt = 0; nt < 4; ++nt)
                acc[mt][nt] = __builtin_amdgcn_mfma_f32_16x16x32_f16(a[mt], b[nt], acc[mt][nt], 0, 0, 0);
        __syncthreads();
    }
    #pragma unroll
    for (int nt = 0; nt < 4; ++nt) {
        const int n = nBase + wn + nt * 16 + l16;
        const float s = scale[n], bz = bias[n];
        #pragma unroll
        for (int mt = 0; mt < 4; ++mt)
            #pragma unroll
            for (int r = 0; r < 4; ++r)
                out[(size_t)(mBase + wm + mt * 16 + quad * 4 + r) * N_TOTAL + n] = acc[mt][nt][r] * s + bz;
    }
}

extern "C" void kernel_launch(void* const* d_in, const int* in_sizes, int n_in,
                              void* d_out, int out_size, void* d_ws, size_t ws_size,
                              hipStream_t stream) {
    const float* x     = (const float*)d_in[0];
    const int*   wp    = (const int*)d_in[1];
    const float* scale = (const float*)d_in[2];
    const float* bias  = (const float*)d_in[3];
    float*       out   = (float*)d_out;

    const size_t xf_bytes = (size_t)M_TOTAL * K_TOTAL * 2;              // 32 MB
    const size_t wf_bytes = (size_t)N_TOTAL * K_TOTAL * 2;              // 86 MB
    dim3 grid(N_TOTAL / BN, M_TOTAL / BM);                               // (86, 32)

    if (ws_size >= xf_bytes + wf_bytes) {
        _Float16* xf = (_Float16*)d_ws;
        _Float16* wf = (_Float16*)((char*)d_ws + xf_bytes);
        // prepass: 16,777,216 floats / 8 per thread = 8192 blocks
        _Int4Linear_cvt_x<<<8192, 256, 0, stream>>>(x, xf);
        // prepass: 22,544,384 int32 / 4 per thread = 22016 blocks
        _Int4Linear_dequant_w<<<22016, 256, 0, stream>>>(wp, wf);
        _Int4Linear_54631984005366_kernel<<<grid, 256, 0, stream>>>(xf, wf, scale, bias, out);
    } else {
        _Int4Linear_fallback<<<grid, 256, 0, stream>>>(x, wp, scale, bias, out);
    }
}